// Round 3
// baseline (4642.181 us; speedup 1.0000x reference)
//
#include <hip/hip_runtime.h>
#include <hip/hip_bf16.h>

// Problem constants (bert-base captioning decoder)
#define VCB 30522   // vocab
#define EMB 512     // embed size
#define ATTD 512    // attention dim
#define ENC 2048    // encoder dim
#define HD 512      // hidden dim
#define BB 32       // batch
#define NF 49       // image features
#define TSTEPS 20   // decode steps
#define EIN 2560    // EMB + ENC (lstm input)

typedef __attribute__((ext_vector_type(8))) __bf16 bf16x8;
typedef __attribute__((ext_vector_type(8))) float floatx8;
typedef __attribute__((ext_vector_type(4))) float floatx4;
typedef __hip_bfloat16 bf16;

__device__ __forceinline__ float bf2f(bf16 x){ return __bfloat162float(x); }
__device__ __forceinline__ bf16 f2bf(float x){ return __float2bfloat16(x); }
__device__ __forceinline__ float sigm(float x){ return 1.0f/(1.0f+expf(-x)); }

// ---- dtype-adaptive load/store helpers (f=1: data is f32; f=0: bf16) ------
__device__ __forceinline__ float ld1(const void* base, size_t idx, int f){
    if (f) return ((const float*)base)[idx];
    return bf2f(((const bf16*)base)[idx]);
}
__device__ __forceinline__ floatx8 ld8(const void* base, size_t idx, int f){
    floatx8 r;
    if (f){
        const float* p = (const float*)base + idx;
        float4 a = *(const float4*)p, b = *(const float4*)(p+4);
        r[0]=a.x; r[1]=a.y; r[2]=a.z; r[3]=a.w; r[4]=b.x; r[5]=b.y; r[6]=b.z; r[7]=b.w;
    } else {
        bf16x8 v = *(const bf16x8*)((const bf16*)base + idx);
#pragma unroll
        for (int i = 0; i < 8; ++i) r[i] = (float)v[i];
    }
    return r;
}
__device__ __forceinline__ bf16x8 ldbf8(const void* base, size_t idx, int f){
    if (f){
        const float* p = (const float*)base + idx;
        bf16x8 r;
#pragma unroll
        for (int i = 0; i < 8; ++i) r[i] = (__bf16)p[i];
        return r;
    }
    return *(const bf16x8*)((const bf16*)base + idx);
}
__device__ __forceinline__ bf16x8 bf8_of_f32(const float* p){
    bf16x8 r;
#pragma unroll
    for (int i = 0; i < 8; ++i) r[i] = (__bf16)p[i];
    return r;
}
__device__ __forceinline__ void st1(void* base, size_t idx, float v, int f){
    if (f) ((float*)base)[idx] = v;
    else   ((bf16*)base)[idx] = f2bf(v);
}
__device__ __forceinline__ float dot8f(floatx8 a, floatx8 b){
    float s = 0.f;
#pragma unroll
    for (int i = 0; i < 8; ++i) s += a[i]*b[i];
    return s;
}

#define MFMA16(a,b,c) __builtin_amdgcn_mfma_f32_16x16x32_bf16(a,b,c,0,0,0)
// Verified fragment layout (learn_hip m89/m91):
//   A: lane holds A[m=lane&15][k=(lane>>4)*8+j]   (row-major [M][K])
//   B: lane holds Bt[n=lane&15][k=(lane>>4)*8+j]  (row-major [N][K])
//   D: lane holds D[row=(lane>>4)*4+r][col=lane&15]

// ---------------- kernel 0: dtype detect -----------------------------------
// bf16 emb data ~N(0,0.02): every half-word has tiny exponent. f32 emb data:
// low half-words are mantissa garbage -> huge bf16 exponents w.p. ~1.
__global__ void k_detect(const void* emb, int* flag){
    int tid = threadIdx.x;
    __shared__ int bad;
    if (tid == 0) bad = 0;
    __syncthreads();
    const unsigned short* u = (const unsigned short*)emb;
    int local = 0;
    for (int i = tid; i < 4096; i += 256){
        int e = (u[i] >> 7) & 0xFF;
        if (e > 140) local = 1;           // |v| > 2^13: impossible for real data
    }
    if (local) bad = 1;                   // benign race, all write 1
    __syncthreads();
    if (tid == 0) *flag = bad;
}

// ---------------- kernel 1: mean over feature positions (f32 out) ----------
__global__ void k_mean(const void* feat, float* __restrict__ mean_f,
                       const int* __restrict__ flag){
    int f = *flag;
    int b = blockIdx.x, tid = threadIdx.x;
    for (int i = 0; i < ENC/256; ++i){
        int e = i*256 + tid;
        size_t base = (size_t)b*NF*ENC + e;
        float s = 0.f;
        for (int n = 0; n < NF; ++n) s += ld1(feat, base + (size_t)n*ENC, f);
        mean_f[b*ENC + e] = s * (1.0f/49.0f);
    }
}

// ---------------- kernel 2: h0/c0 = mean_f @ [ihw|icw]^T + b (VALU) --------
// thread = one (b, n): n<512 -> Hbuf row (step 0), else c_f32.
__global__ void k_init_hc(const float* __restrict__ mean_f,
                          const void* ihw, const void* ihb,
                          const void* icw, const void* icb,
                          float* __restrict__ Hbuf, float* __restrict__ c_f32,
                          const int* __restrict__ flag){
    int f = *flag;
    int idx = blockIdx.x*256 + threadIdx.x;       // 0..32767
    int b = idx >> 10, n = idx & 1023;
    const void* w = (n < HD) ? ihw : icw;
    size_t wrow = (size_t)(n < HD ? n : n - HD)*ENC;
    const float* mp = mean_f + b*ENC;
    float acc = 0.f;
    for (int k = 0; k < ENC; k += 8){
        floatx8 wv = ld8(w, wrow + k, f);
        float4 a0 = *(const float4*)(mp + k);
        float4 a1 = *(const float4*)(mp + k + 4);
        acc += a0.x*wv[0] + a0.y*wv[1] + a0.z*wv[2] + a0.w*wv[3]
             + a1.x*wv[4] + a1.y*wv[5] + a1.z*wv[6] + a1.w*wv[7];
    }
    if (n < HD) Hbuf[b*HD + n]      = acc + ld1(ihb, n, f);
    else        c_f32[b*HD + (n-HD)] = acc + ld1(icb, n - HD, f);
}

// ---------------- kernel 3: u_hs = feat @ U_w^T + U_b (MFMA, f32 out) ------
// M=1568 (=98*16), N=512, K=2048. grid (98, 8), 4 waves x 16-col n-tiles.
__global__ void k_uhs(const void* feat, const void* U_w, const void* U_b,
                      float* __restrict__ u_hs, const int* __restrict__ flag){
    int f = *flag;
    int tid = threadIdx.x, wave = tid>>6, lane = tid&63, quad = lane>>4, lq = lane&15;
    int m0 = blockIdx.x*16;
    int n0 = blockIdx.y*64 + wave*16;
    size_t arow = (size_t)(m0+lq)*ENC;
    size_t brow = (size_t)(n0+lq)*ENC;
    floatx4 acc = {0,0,0,0};
    for (int kk = 0; kk < ENC/32; ++kk){
        int k = kk*32 + quad*8;
        bf16x8 afr = ldbf8(feat, arow + k, f);
        bf16x8 bfr = ldbf8(U_w,  brow + k, f);
        acc = MFMA16(afr, bfr, acc);
    }
    float ub = ld1(U_b, n0+lq, f);
    for (int r = 0; r < 4; ++r){
        int m = m0 + quad*4 + r;
        u_hs[(size_t)m*ATTD + n0 + lq] = acc[r] + ub;
    }
}

// ---------------- kernel 4: w_ah = h @ W_w^T + W_b (f32, VALU) -------------
__global__ void k_wah(const float* __restrict__ h, const void* W_w, const void* W_b,
                      float* __restrict__ w_ah, const int* __restrict__ flag){
    int f = *flag;
    int tid = threadIdx.x;
    int b = tid & 31;
    int a = blockIdx.x*8 + (tid>>5);
    const float* hp = h + b*HD;
    size_t wrow = (size_t)a*HD;
    float acc = 0.f;
    for (int k = 0; k < HD; k += 8){
        floatx8 wv = ld8(W_w, wrow + k, f);
        float4 ha = *(const float4*)(hp + k);
        float4 hb = *(const float4*)(hp + k + 4);
        acc += ha.x*wv[0] + ha.y*wv[1] + ha.z*wv[2] + ha.w*wv[3]
             + hb.x*wv[4] + hb.y*wv[5] + hb.z*wv[6] + hb.w*wv[7];
    }
    w_ah[b*ATTD + a] = acc + ld1(W_b, a, f);
}

// ---------------- kernel 5: attention scores/softmax/context/lstm_in -------
// grid (32 batch, 2 e-halves), block 256. lstm_in is f32 now.
__global__ void k_att(int t, const float* __restrict__ u_hs, const float* __restrict__ w_ah,
                      const void* A_w, const void* A_b,
                      const int* __restrict__ captions, const void* emb, const void* feat,
                      float* __restrict__ lstm_in, void* d_out,
                      const int* __restrict__ flag){
    int f = *flag;
    int b = blockIdx.x, half = blockIdx.y, tid = threadIdx.x;
    int wave = tid>>6, lane = tid&63;
    __shared__ float wah_s[ATTD], aw_s[ATTD], sc_s[52], alpha_s[52];
    for (int i = tid; i < ATTD; i += 256){ wah_s[i] = w_ah[b*ATTD + i]; aw_s[i] = ld1(A_w, i, f); }
    if (half == 0){
        int cap = captions[b*21 + t];
        for (int e = tid; e < EMB; e += 256)
            lstm_in[(size_t)b*EIN + e] = ld1(emb, (size_t)cap*EMB + e, f);
    }
    __syncthreads();
    for (int n = wave; n < NF; n += 4){
        const float* up = u_hs + (size_t)(b*NF + n)*ATTD;
        float p = 0.f;
        for (int a = lane; a < ATTD; a += 64) p += tanhf(up[a] + wah_s[a]) * aw_s[a];
        for (int off = 32; off; off >>= 1) p += __shfl_down(p, off);
        if (lane == 0) sc_s[n] = p + ld1(A_b, 0, f);
    }
    __syncthreads();
    if (wave == 0){
        float v = (lane < NF) ? sc_s[lane] : -1e30f;
        float mx = v;
        for (int off = 32; off; off >>= 1) mx = fmaxf(mx, __shfl_down(mx, off));
        mx = __shfl(mx, 0);
        float e = (lane < NF) ? expf(v - mx) : 0.f;
        float s = e;
        for (int off = 32; off; off >>= 1) s += __shfl_down(s, off);
        s = __shfl(s, 0);
        if (lane < NF){
            float al = e / s;
            alpha_s[lane] = al;
            if (half == 0)
                st1(d_out, (size_t)BB*TSTEPS*VCB + (size_t)b*(TSTEPS*NF) + t*NF + lane, al, f);
        }
    }
    __syncthreads();
    int e0 = half*1024;
    for (int i = 0; i < 4; ++i){
        int e = e0 + i*256 + tid;
        size_t base = (size_t)b*NF*ENC + e;
        float acc = 0.f;
        for (int n = 0; n < NF; ++n) acc += alpha_s[n] * ld1(feat, base + (size_t)n*ENC, f);
        lstm_in[(size_t)b*EIN + EMB + e] = acc;
    }
}

// ---------------- kernel 6: LSTM gates (VALU) + fused pointwise ------------
// gates = [x|ctx] @ w_ih^T + h_prev @ w_hh^T + b_ih + b_hh ; order i,f,g,o
// grid 256 blocks x 256 thr. Block owns 2 cols x 32 b. Thread = (pair p, kseg).
__global__ void k_gates(const float* __restrict__ lstm_in, const float* __restrict__ h_prev,
                        const void* w_ih, const void* w_hh,
                        const void* b_ih_p, const void* b_hh_p,
                        float* __restrict__ c_f32, float* __restrict__ h_out,
                        const int* __restrict__ flag){
    int f = *flag;
    int tid = threadIdx.x;
    int p = tid & 63, ks = tid >> 6;
    int b = p & 31, dc = p >> 5;
    int col = blockIdx.x*2 + dc;
    const float* xrow = lstm_in + (size_t)b*EIN;
    const float* hrow = h_prev + (size_t)b*HD;
    int k0 = ks*768;
    float G[4];
#pragma unroll
    for (int g = 0; g < 4; ++g){
        int wr = g*HD + col;
        size_t wl = (size_t)wr*EIN;
        size_t wh = (size_t)wr*HD;
        float acc = 0.f;
        for (int kk = 0; kk < 768; kk += 8){
            int k = k0 + kk;
            floatx8 xv, wv;
            if (k < EIN){
                const float* xp = xrow + k;
                float4 a0 = *(const float4*)xp, a1 = *(const float4*)(xp+4);
                xv[0]=a0.x; xv[1]=a0.y; xv[2]=a0.z; xv[3]=a0.w;
                xv[4]=a1.x; xv[5]=a1.y; xv[6]=a1.z; xv[7]=a1.w;
                wv = ld8(w_ih, wl + k, f);
            } else {
                int kh = k - EIN;
                const float* hp = hrow + kh;
                float4 a0 = *(const float4*)hp, a1 = *(const float4*)(hp+4);
                xv[0]=a0.x; xv[1]=a0.y; xv[2]=a0.z; xv[3]=a0.w;
                xv[4]=a1.x; xv[5]=a1.y; xv[6]=a1.z; xv[7]=a1.w;
                wv = ld8(w_hh, wh + kh, f);
            }
            acc += dot8f(xv, wv);
        }
        G[g] = acc;
    }
    __shared__ float red[4][4][64];   // [kseg][gate][pair]
#pragma unroll
    for (int g = 0; g < 4; ++g) red[ks][g][p] = G[g];
    __syncthreads();
    if (tid < 64){
        int pb = tid & 31, pdc = tid >> 5;
        int pcol = blockIdx.x*2 + pdc;
        float Gf[4];
#pragma unroll
        for (int g = 0; g < 4; ++g){
            int wr = g*HD + pcol;
            Gf[g] = red[0][g][tid] + red[1][g][tid] + red[2][g][tid] + red[3][g][tid]
                  + ld1(b_ih_p, wr, f) + ld1(b_hh_p, wr, f);
        }
        float c_old = c_f32[pb*HD + pcol];
        float c_new = sigm(Gf[1])*c_old + sigm(Gf[0])*tanhf(Gf[2]);
        float h_new = sigm(Gf[3])*tanhf(c_new);
        c_f32[pb*HD + pcol] = c_new;
        h_out[pb*HD + pcol] = h_new;    // Hbuf row t+1
    }
}

// ---------------- kernel 7: preds = Hbuf[1..20] @ fcn_w^T + fcn_b (MFMA) ---
// M=640 (m = t*32+b -> Hbuf row m+32), N=30522, K=512. grid (477, 4).
__global__ void __launch_bounds__(256) k_fcn(const float* __restrict__ Hbuf,
                                             const void* fcn_w, const void* fcn_b,
                                             void* d_out, const int* __restrict__ flag){
    int f = *flag;
    int tid = threadIdx.x, wave = tid>>6, lane = tid&63, quad = lane>>4, lq = lane&15;
    int n0 = blockIdx.x*64 + wave*16;
    int v = n0 + lq;
    int vc = (v < VCB) ? v : (VCB-1);
    size_t brow = (size_t)vc*HD;
    bf16x8 bfr[16];
    for (int kk = 0; kk < 16; ++kk) bfr[kk] = ldbf8(fcn_w, brow + kk*32 + quad*8, f);
    float bias = ld1(fcn_b, vc, f);
    int mbase0 = blockIdx.y*160;
    for (int mt = 0; mt < 10; ++mt){
        int mbase = mbase0 + mt*16;
        const float* arow = Hbuf + (size_t)(mbase + lq + 32)*HD;  // +32: skip h0 rows
        floatx4 acc = {0,0,0,0};
        for (int kk = 0; kk < 16; ++kk){
            bf16x8 afr = bf8_of_f32(arow + kk*32 + quad*8);
            acc = MFMA16(afr, bfr[kk], acc);
        }
        if (v < VCB){
            for (int r = 0; r < 4; ++r){
                int m = mbase + quad*4 + r;
                int b = m & 31, tt = m >> 5;
                st1(d_out, (size_t)b*(TSTEPS*VCB) + (size_t)tt*VCB + v, acc[r] + bias, f);
            }
        }
    }
}

// ---------------- host launch ---------------------------------------------
extern "C" void kernel_launch(void* const* d_in, const int* in_sizes, int n_in,
                              void* d_out, int out_size, void* d_ws, size_t ws_size,
                              hipStream_t stream) {
    const void* feat  = d_in[0];
    const int*  caps  = (const int*)d_in[1];
    const void* emb   = d_in[2];
    const void* W_w   = d_in[3];
    const void* W_b   = d_in[4];
    const void* U_w   = d_in[5];
    const void* U_b   = d_in[6];
    const void* A_w   = d_in[7];
    const void* A_b   = d_in[8];
    const void* ihw   = d_in[9];
    const void* ihb   = d_in[10];
    const void* icw   = d_in[11];
    const void* icb   = d_in[12];
    const void* w_ih  = d_in[13];
    const void* w_hh  = d_in[14];
    const void* b_ih  = d_in[15];
    const void* b_hh  = d_in[16];
    const void* fcn_w = d_in[17];
    const void* fcn_b = d_in[18];

    // workspace layout (16B-aligned)
    char* ws = (char*)d_ws;
    const size_t SZ_UHS  = (size_t)BB*NF*ATTD*4;        // 3,211,264
    const size_t SZ_C    = (size_t)BB*HD*4;             //    65,536
    const size_t SZ_WAH  = (size_t)BB*ATTD*4;           //    65,536
    const size_t SZ_MEAN = (size_t)BB*ENC*4;            //   262,144
    const size_t SZ_LIN  = (size_t)BB*EIN*4;            //   327,680
    const size_t SZ_HBUF = (size_t)(TSTEPS+1)*BB*HD*4;  // 1,376,256
    size_t off = 0;
    float* u_hs    = (float*)(ws + off); off += SZ_UHS;
    float* c_f32   = (float*)(ws + off); off += SZ_C;
    float* w_ah    = (float*)(ws + off); off += SZ_WAH;
    float* mean_f  = (float*)(ws + off); off += SZ_MEAN;
    float* lstm_in = (float*)(ws + off); off += SZ_LIN;
    float* Hbuf    = (float*)(ws + off); off += SZ_HBUF;
    int*   flag    = (int*)  (ws + off); off += 256;
    if (ws_size < off) return;

    k_detect <<<1, 256, 0, stream>>>(emb, flag);
    k_mean   <<<BB, 256, 0, stream>>>(feat, mean_f, flag);
    k_init_hc<<<128, 256, 0, stream>>>(mean_f, ihw, ihb, icw, icb, Hbuf, c_f32, flag);
    k_uhs    <<<dim3(98, 8), 256, 0, stream>>>(feat, U_w, U_b, u_hs, flag);

    for (int t = 0; t < TSTEPS; ++t){
        float* h_t = Hbuf + (size_t)t*BB*HD;
        k_wah  <<<64, 256, 0, stream>>>(h_t, W_w, W_b, w_ah, flag);
        k_att  <<<dim3(BB, 2), 256, 0, stream>>>(t, u_hs, w_ah, A_w, A_b, caps, emb, feat,
                                                 lstm_in, d_out, flag);
        k_gates<<<256, 256, 0, stream>>>(lstm_in, h_t, w_ih, w_hh, b_ih, b_hh,
                                         c_f32, h_t + BB*HD, flag);
    }
    k_fcn<<<dim3(477, 4), 256, 0, stream>>>(Hbuf, fcn_w, fcn_b, d_out, flag);
}

// Round 4
// 2710.456 us; speedup vs baseline: 1.7127x; 1.7127x over previous
//
#include <hip/hip_runtime.h>
#include <hip/hip_bf16.h>

// Problem constants (bert-base captioning decoder)
#define VCB 30522   // vocab
#define EMB 512     // embed size
#define ATTD 512    // attention dim
#define ENC 2048    // encoder dim
#define HD 512      // hidden dim
#define BB 32       // batch
#define NF 49       // image features
#define TSTEPS 20   // decode steps
#define EIN 2560    // EMB + ENC (lstm input)
#define KCAT 3072   // EIN + HD (fused gate GEMM K)

typedef __attribute__((ext_vector_type(8))) __bf16 bf16x8;
typedef __attribute__((ext_vector_type(8))) float floatx8;
typedef __attribute__((ext_vector_type(4))) float floatx4;
typedef __hip_bfloat16 bf16;

__device__ __forceinline__ float bf2f(bf16 x){ return __bfloat162float(x); }
__device__ __forceinline__ bf16 f2bf(float x){ return __float2bfloat16(x); }
__device__ __forceinline__ float sigm(float x){ return 1.0f/(1.0f+expf(-x)); }

// ---- dtype-adaptive load/store helpers (f=1: data is f32; f=0: bf16) ------
__device__ __forceinline__ float ld1(const void* base, size_t idx, int f){
    if (f) return ((const float*)base)[idx];
    return bf2f(((const bf16*)base)[idx]);
}
__device__ __forceinline__ bf16x8 ldbf8(const void* base, size_t idx, int f){
    if (f){
        const float* p = (const float*)base + idx;
        bf16x8 r;
#pragma unroll
        for (int i = 0; i < 8; ++i) r[i] = (__bf16)p[i];
        return r;
    }
    return *(const bf16x8*)((const bf16*)base + idx);
}
__device__ __forceinline__ void st1(void* base, size_t idx, float v, int f){
    if (f) ((float*)base)[idx] = v;
    else   ((bf16*)base)[idx] = f2bf(v);
}

#define MFMA16(a,b,c) __builtin_amdgcn_mfma_f32_16x16x32_bf16(a,b,c,0,0,0)
// Verified fragment layout (learn_hip m89/m91):
//   A: lane holds A[m=lane&15][k=(lane>>4)*8+j]   (row-major [M][K])
//   B: lane holds Bt[n=lane&15][k=(lane>>4)*8+j]  (row-major [N][K])
//   D: lane holds D[row=(lane>>4)*4+r][col=lane&15]

// ---------------- kernel 0: dtype detect -----------------------------------
__global__ void k_detect(const void* emb, int* flag){
    int tid = threadIdx.x;
    __shared__ int bad;
    if (tid == 0) bad = 0;
    __syncthreads();
    const unsigned short* u = (const unsigned short*)emb;
    int local = 0;
    for (int i = tid; i < 4096; i += 256){
        int e = (u[i] >> 7) & 0xFF;
        if (e > 140) local = 1;           // |v| > 2^13: impossible for real data
    }
    if (local) bad = 1;
    __syncthreads();
    if (tid == 0) *flag = bad;
}

// ---------------- prep kernels: convert weights to bf16 once ---------------
// wcat[r][0..2559] = w_ih[r], wcat[r][2560..3071] = w_hh[r]   (r = gate*512+n)
__global__ void k_prep_gates(const void* w_ih, const void* w_hh, bf16* __restrict__ wcat,
                             const int* __restrict__ flag){
    int ff = *flag;
    int r = blockIdx.x, tid = threadIdx.x;
    for (int i = tid; i < KCAT; i += 256){
        float v = (i < EIN) ? ld1(w_ih, (size_t)r*EIN + i, ff)
                            : ld1(w_hh, (size_t)r*HD + (i - EIN), ff);
        wcat[(size_t)r*KCAT + i] = f2bf(v);
    }
}
__global__ void k_prep_cvt(const void* src, bf16* __restrict__ dst, size_t n,
                           const int* __restrict__ flag){
    int ff = *flag;
    size_t idx = (size_t)blockIdx.x*256 + threadIdx.x;
    size_t stride = (size_t)gridDim.x*256;
    for (size_t i = idx; i < n; i += stride) dst[i] = f2bf(ld1(src, i, ff));
}

// ---------------- kernel 1: mean over feature positions (f32 out) ----------
__global__ void k_mean(const void* feat, float* __restrict__ mean_f,
                       const int* __restrict__ flag){
    int ff = *flag;
    int b = blockIdx.x, tid = threadIdx.x;
    for (int i = 0; i < ENC/256; ++i){
        int e = i*256 + tid;
        size_t base = (size_t)b*NF*ENC + e;
        float s = 0.f;
        for (int n = 0; n < NF; ++n) s += ld1(feat, base + (size_t)n*ENC, ff);
        mean_f[b*ENC + e] = s * (1.0f/49.0f);
    }
}

// ---------------- kernel 2: h0/c0 = mean_f @ [ihw|icw]^T + b (VALU) --------
__global__ void k_init_hc(const float* __restrict__ mean_f,
                          const void* ihw, const void* ihb,
                          const void* icw, const void* icb,
                          float* __restrict__ Hbuf, float* __restrict__ c_f32,
                          const int* __restrict__ flag){
    int ff = *flag;
    int idx = blockIdx.x*256 + threadIdx.x;       // 0..32767
    int b = idx >> 10, n = idx & 1023;
    const void* w = (n < HD) ? ihw : icw;
    size_t wrow = (size_t)(n < HD ? n : n - HD)*ENC;
    const float* mp = mean_f + b*ENC;
    float acc = 0.f;
    for (int k = 0; k < ENC; k += 8){
        bf16x8 wv = ldbf8(w, wrow + k, 0 /*unused*/), dummy;
        (void)dummy;
        // load weights at full precision:
        float w0 = ld1(w, wrow+k+0, ff), w1 = ld1(w, wrow+k+1, ff);
        float w2 = ld1(w, wrow+k+2, ff), w3 = ld1(w, wrow+k+3, ff);
        float w4 = ld1(w, wrow+k+4, ff), w5 = ld1(w, wrow+k+5, ff);
        float w6 = ld1(w, wrow+k+6, ff), w7 = ld1(w, wrow+k+7, ff);
        float4 a0 = *(const float4*)(mp + k);
        float4 a1 = *(const float4*)(mp + k + 4);
        acc += a0.x*w0 + a0.y*w1 + a0.z*w2 + a0.w*w3
             + a1.x*w4 + a1.y*w5 + a1.z*w6 + a1.w*w7;
    }
    if (n < HD) Hbuf[b*HD + n]       = acc + ld1(ihb, n, ff);
    else        c_f32[b*HD + (n-HD)] = acc + ld1(icb, n - HD, ff);
}

// ---------------- kernel 3: u_hs = feat @ U_w^T + U_b (MFMA, f32 out) ------
__global__ void k_uhs(const void* feat, const void* U_w, const void* U_b,
                      float* __restrict__ u_hs, const int* __restrict__ flag){
    int ff = *flag;
    int tid = threadIdx.x, wave = tid>>6, lane = tid&63, quad = lane>>4, lq = lane&15;
    int m0 = blockIdx.x*16;
    int n0 = blockIdx.y*64 + wave*16;
    size_t arow = (size_t)(m0+lq)*ENC;
    size_t brow = (size_t)(n0+lq)*ENC;
    floatx4 acc = {0,0,0,0};
    for (int kk = 0; kk < ENC/32; ++kk){
        int k = kk*32 + quad*8;
        bf16x8 afr = ldbf8(feat, arow + k, ff);
        bf16x8 bfr = ldbf8(U_w,  brow + k, ff);
        acc = MFMA16(afr, bfr, acc);
    }
    float ub = ld1(U_b, n0+lq, ff);
    for (int r = 0; r < 4; ++r){
        int m = m0 + quad*4 + r;
        u_hs[(size_t)m*ATTD + n0 + lq] = acc[r] + ub;
    }
}

// ---------------- kernel 4: per-step attention (one block per b) -----------
// Builds lstm_in_bf[b][0..3071] = [embed | context | h_prev] (bf16 A-matrix)
// + writes alphas. W_w pre-converted to bf16 (lanes span a-rows: coalesced).
__global__ void k_step1(int t, const float* __restrict__ Hbuf_t,
                        const bf16* __restrict__ Ww_bf, const void* W_b,
                        const float* __restrict__ u_hs, const void* A_w, const void* A_b,
                        const int* __restrict__ captions, const void* emb, const void* feat,
                        bf16* __restrict__ lstm_in_bf, void* d_out,
                        const int* __restrict__ flag){
    int ff = *flag;
    int b = blockIdx.x, tid = threadIdx.x, wave = tid>>6, lane = tid&63;
    __shared__ float h_s[HD], wah_s[ATTD], aw_s[ATTD], sc_s[52], alpha_s[52];
    for (int i = tid; i < HD; i += 256){
        float hv = Hbuf_t[b*HD + i];
        h_s[i] = hv;
        lstm_in_bf[(size_t)b*KCAT + EIN + i] = f2bf(hv);
        aw_s[i] = ld1(A_w, i, ff);
    }
    int cap = captions[b*21 + t];
    for (int e = tid; e < EMB; e += 256)
        lstm_in_bf[(size_t)b*KCAT + e] = f2bf(ld1(emb, (size_t)cap*EMB + e, ff));
    __syncthreads();
    // phase A: w_ah[a] = h . W_w[a] + W_b[a]  (2 rows per thread)
    for (int a = tid; a < ATTD; a += 256){
        const bf16* wr = Ww_bf + (size_t)a*HD;
        float acc = 0.f;
        for (int k = 0; k < HD; k += 8){
            bf16x8 wv = *(const bf16x8*)(wr + k);
            acc += (float)wv[0]*h_s[k+0] + (float)wv[1]*h_s[k+1]
                 + (float)wv[2]*h_s[k+2] + (float)wv[3]*h_s[k+3]
                 + (float)wv[4]*h_s[k+4] + (float)wv[5]*h_s[k+5]
                 + (float)wv[6]*h_s[k+6] + (float)wv[7]*h_s[k+7];
        }
        wah_s[a] = acc + ld1(W_b, a, ff);
    }
    __syncthreads();
    // phase B: scores[n] = A_w . tanh(u_hs[b,n,:] + w_ah) + A_b
    for (int n = wave; n < NF; n += 4){
        const float* up = u_hs + (size_t)(b*NF + n)*ATTD;
        float p = 0.f;
        for (int a = lane; a < ATTD; a += 64) p += tanhf(up[a] + wah_s[a]) * aw_s[a];
        for (int off = 32; off; off >>= 1) p += __shfl_down(p, off);
        if (lane == 0) sc_s[n] = p + ld1(A_b, 0, ff);
    }
    __syncthreads();
    // phase C: softmax over 49 (wave 0) + alpha output
    if (wave == 0){
        float v = (lane < NF) ? sc_s[lane] : -1e30f;
        float mx = v;
        for (int off = 32; off; off >>= 1) mx = fmaxf(mx, __shfl_down(mx, off));
        mx = __shfl(mx, 0);
        float e = (lane < NF) ? expf(v - mx) : 0.f;
        float s = e;
        for (int off = 32; off; off >>= 1) s += __shfl_down(s, off);
        s = __shfl(s, 0);
        if (lane < NF){
            float al = e / s;
            alpha_s[lane] = al;
            st1(d_out, (size_t)BB*TSTEPS*VCB + (size_t)b*(TSTEPS*NF) + t*NF + lane, al, ff);
        }
    }
    __syncthreads();
    // phase D: context[e] = sum_n alpha[n]*feat[b,n,e]  (8 acc regs, n outer)
    float acc[8] = {0,0,0,0,0,0,0,0};
    for (int n = 0; n < NF; ++n){
        float al = alpha_s[n];
        size_t base = (size_t)b*NF*ENC + (size_t)n*ENC + tid;
#pragma unroll
        for (int i = 0; i < 8; ++i) acc[i] += al * ld1(feat, base + i*256, ff);
    }
#pragma unroll
    for (int i = 0; i < 8; ++i)
        lstm_in_bf[(size_t)b*KCAT + EMB + i*256 + tid] = f2bf(acc[i]);
}

// ---------------- kernel 5: gates GEMM (MFMA) + fused LSTM pointwise -------
// gates[32 x 2048] = lstm_in_bf[32 x 3072] @ wcat^T ; M=32, N=2048, K=3072.
// grid 128: block owns 4 hidden cols x 4 gates (16 interleaved B-rows).
// K split 4 ways across waves, LDS reduce, pointwise in tid<128.
__global__ void k_step2(const bf16* __restrict__ lstm_in_bf, const bf16* __restrict__ wcat,
                        const void* b_ih, const void* b_hh,
                        float* __restrict__ c_f32, float* __restrict__ Hbuf_next,
                        bf16* __restrict__ Hall_bf_t, const int* __restrict__ flag){
    int ff = *flag;
    int tid = threadIdx.x, ks = tid>>6, lane = tid&63, quad = lane>>4, lq = lane&15;
    int n0 = blockIdx.x*4;
    int gate = lq>>2, j = lq&3;
    const bf16* brow = wcat + (size_t)(gate*HD + n0 + j)*KCAT;
    floatx4 acc[2] = {{0,0,0,0},{0,0,0,0}};
    int kb = ks*768;
    for (int kk = 0; kk < 24; ++kk){
        int k = kb + kk*32 + quad*8;
        bf16x8 bfr = *(const bf16x8*)(brow + k);
#pragma unroll
        for (int mt = 0; mt < 2; ++mt){
            bf16x8 afr = *(const bf16x8*)(lstm_in_bf + (size_t)(mt*16+lq)*KCAT + k);
            acc[mt] = MFMA16(afr, bfr, acc[mt]);
        }
    }
    __shared__ float red[4][2][16][16];
#pragma unroll
    for (int mt = 0; mt < 2; ++mt)
        for (int r = 0; r < 4; ++r)
            red[ks][mt][quad*4+r][lq] = acc[mt][r];
    __syncthreads();
    if (tid < 128){
        int bb = tid & 31, jj = tid >> 5;     // jj 0..3
        int col = n0 + jj;
        float G[4];
#pragma unroll
        for (int g = 0; g < 4; ++g){
            int lqv = g*4 + jj;
            float s = red[0][bb>>4][bb&15][lqv] + red[1][bb>>4][bb&15][lqv]
                    + red[2][bb>>4][bb&15][lqv] + red[3][bb>>4][bb&15][lqv];
            G[g] = s + ld1(b_ih, g*HD + col, ff) + ld1(b_hh, g*HD + col, ff);
        }
        float c_old = c_f32[bb*HD + col];
        float c_new = sigm(G[1])*c_old + sigm(G[0])*tanhf(G[2]);
        float h_new = sigm(G[3])*tanhf(c_new);
        c_f32[bb*HD + col] = c_new;
        Hbuf_next[bb*HD + col] = h_new;
        Hall_bf_t[(size_t)bb*HD + col] = f2bf(h_new);
    }
}

// ---------------- kernel 6: preds = Hall_bf @ fcnw_bf^T + fcn_b ------------
// M=640 (m=t*32+b), N=30522, K=512. grid 477 (x only): fcn_w read EXACTLY once.
__global__ void __launch_bounds__(256) k_fcn(const bf16* __restrict__ Hall_bf,
                                             const bf16* __restrict__ fcnw_bf,
                                             const void* fcn_b, void* d_out,
                                             const int* __restrict__ flag){
    int ff = *flag;
    int tid = threadIdx.x, wave = tid>>6, lane = tid&63, quad = lane>>4, lq = lane&15;
    int n0 = blockIdx.x*64 + wave*16;
    int v = n0 + lq;
    int vc = (v < VCB) ? v : (VCB-1);
    const bf16* brow = fcnw_bf + (size_t)vc*HD;
    bf16x8 bfr[16];
#pragma unroll
    for (int kk = 0; kk < 16; ++kk) bfr[kk] = *(const bf16x8*)(brow + kk*32 + quad*8);
    float bias = ld1(fcn_b, vc, ff);
    for (int mt = 0; mt < 40; ++mt){
        const bf16* arow = Hall_bf + (size_t)(mt*16 + lq)*HD;
        floatx4 acc = {0,0,0,0};
#pragma unroll
        for (int kk = 0; kk < 16; ++kk){
            bf16x8 afr = *(const bf16x8*)(arow + kk*32 + quad*8);
            acc = MFMA16(afr, bfr[kk], acc);
        }
        if (v < VCB){
#pragma unroll
            for (int r = 0; r < 4; ++r){
                int m = mt*16 + quad*4 + r;
                int b = m & 31, tt = m >> 5;
                st1(d_out, (size_t)b*(TSTEPS*VCB) + (size_t)tt*VCB + v, acc[r] + bias, ff);
            }
        }
    }
}

// ---------------- host launch ---------------------------------------------
extern "C" void kernel_launch(void* const* d_in, const int* in_sizes, int n_in,
                              void* d_out, int out_size, void* d_ws, size_t ws_size,
                              hipStream_t stream) {
    const void* feat  = d_in[0];
    const int*  caps  = (const int*)d_in[1];
    const void* emb   = d_in[2];
    const void* W_w   = d_in[3];
    const void* W_b   = d_in[4];
    const void* U_w   = d_in[5];
    const void* U_b   = d_in[6];
    const void* A_w   = d_in[7];
    const void* A_b   = d_in[8];
    const void* ihw   = d_in[9];
    const void* ihb   = d_in[10];
    const void* icw   = d_in[11];
    const void* icb   = d_in[12];
    const void* w_ih  = d_in[13];
    const void* w_hh  = d_in[14];
    const void* b_ih  = d_in[15];
    const void* b_hh  = d_in[16];
    const void* fcn_w = d_in[17];
    const void* fcn_b = d_in[18];

    // workspace layout (16B-aligned)
    char* ws = (char*)d_ws;
    size_t off = 0;
    float* u_hs    = (float*)(ws + off); off += (size_t)BB*NF*ATTD*4;       // 3.2 MB
    float* c_f32   = (float*)(ws + off); off += (size_t)BB*HD*4;            // 64 KB
    float* mean_f  = (float*)(ws + off); off += (size_t)BB*ENC*4;           // 256 KB
    float* Hbuf    = (float*)(ws + off); off += (size_t)(TSTEPS+1)*BB*HD*4; // 1.38 MB
    bf16*  lstm_in = (bf16*) (ws + off); off += (size_t)BB*KCAT*2;          // 192 KB
    bf16*  Hall_bf = (bf16*) (ws + off); off += (size_t)TSTEPS*BB*HD*2;     // 640 KB
    bf16*  wcat    = (bf16*) (ws + off); off += (size_t)4*HD*KCAT*2;        // 12.6 MB
    bf16*  fcnw_bf = (bf16*) (ws + off); off += (size_t)VCB*HD*2;           // 31.25 MB
    bf16*  Ww_bf   = (bf16*) (ws + off); off += (size_t)ATTD*HD*2;          // 512 KB
    int*   flag    = (int*)  (ws + off); off += 256;
    if (ws_size < off) return;

    k_detect    <<<1, 256, 0, stream>>>(emb, flag);
    k_prep_gates<<<2048, 256, 0, stream>>>(w_ih, w_hh, wcat, flag);
    k_prep_cvt  <<<2048, 256, 0, stream>>>(fcn_w, fcnw_bf, (size_t)VCB*HD, flag);
    k_prep_cvt  <<<256, 256, 0, stream>>>(W_w, Ww_bf, (size_t)ATTD*HD, flag);
    k_mean      <<<BB, 256, 0, stream>>>(feat, mean_f, flag);
    k_init_hc   <<<128, 256, 0, stream>>>(mean_f, ihw, ihb, icw, icb, Hbuf, c_f32, flag);
    k_uhs       <<<dim3(98, 8), 256, 0, stream>>>(feat, U_w, U_b, u_hs, flag);

    for (int t = 0; t < TSTEPS; ++t){
        float* h_t = Hbuf + (size_t)t*BB*HD;
        k_step1<<<BB, 256, 0, stream>>>(t, h_t, Ww_bf, W_b, u_hs, A_w, A_b, caps, emb, feat,
                                        lstm_in, d_out, flag);
        k_step2<<<128, 256, 0, stream>>>(lstm_in, wcat, b_ih, b_hh, c_f32,
                                         h_t + (size_t)BB*HD,
                                         Hall_bf + (size_t)t*BB*HD, flag);
    }
    k_fcn<<<477, 256, 0, stream>>>(Hall_bf, fcnw_bf, fcn_b, d_out, flag);
}

// Round 5
// 1682.312 us; speedup vs baseline: 2.7594x; 1.6111x over previous
//
#include <hip/hip_runtime.h>
#include <hip/hip_bf16.h>

// Problem constants (bert-base captioning decoder)
#define VCB 30522   // vocab
#define EMB 512     // embed size
#define ATTD 512    // attention dim
#define ENC 2048    // encoder dim
#define HD 512      // hidden dim
#define BB 32       // batch
#define NF 49       // image features
#define TSTEPS 20   // decode steps
#define EIN 2560    // EMB + ENC (lstm input)
#define KCAT 3072   // EIN + HD (fused gate GEMM K)

typedef __attribute__((ext_vector_type(8))) __bf16 bf16x8;
typedef __attribute__((ext_vector_type(4))) float floatx4;
typedef __hip_bfloat16 bf16;

__device__ __forceinline__ float bf2f(bf16 x){ return __bfloat162float(x); }
__device__ __forceinline__ bf16 f2bf(float x){ return __float2bfloat16(x); }
__device__ __forceinline__ float sigm(float x){ return 1.0f/(1.0f+expf(-x)); }

// ---- dtype-adaptive load/store helpers (f=1: data is f32; f=0: bf16) ------
__device__ __forceinline__ float ld1(const void* base, size_t idx, int f){
    if (f) return ((const float*)base)[idx];
    return bf2f(((const bf16*)base)[idx]);
}
__device__ __forceinline__ bf16x8 ldbf8(const void* base, size_t idx, int f){
    if (f){
        const float* p = (const float*)base + idx;
        float4 a = *(const float4*)p, b = *(const float4*)(p+4);
        bf16x8 r;
        r[0]=(__bf16)a.x; r[1]=(__bf16)a.y; r[2]=(__bf16)a.z; r[3]=(__bf16)a.w;
        r[4]=(__bf16)b.x; r[5]=(__bf16)b.y; r[6]=(__bf16)b.z; r[7]=(__bf16)b.w;
        return r;
    }
    return *(const bf16x8*)((const bf16*)base + idx);
}
__device__ __forceinline__ bf16x8 bf8_of_f32(const float* p){
    float4 a = *(const float4*)p, b = *(const float4*)(p+4);
    bf16x8 r;
    r[0]=(__bf16)a.x; r[1]=(__bf16)a.y; r[2]=(__bf16)a.z; r[3]=(__bf16)a.w;
    r[4]=(__bf16)b.x; r[5]=(__bf16)b.y; r[6]=(__bf16)b.z; r[7]=(__bf16)b.w;
    return r;
}
__device__ __forceinline__ void st1(void* base, size_t idx, float v, int f){
    if (f) ((float*)base)[idx] = v;
    else   ((bf16*)base)[idx] = f2bf(v);
}

#define MFMA16(a,b,c) __builtin_amdgcn_mfma_f32_16x16x32_bf16(a,b,c,0,0,0)
// Verified fragment layout (learn_hip m89/m91):
//   A: lane holds A[m=lane&15][k=(lane>>4)*8+j]   (row-major [M][K])
//   B: lane holds Bt[n=lane&15][k=(lane>>4)*8+j]  (row-major [N][K])
//   D: lane holds D[row=(lane>>4)*4+r][col=lane&15]

// ---------------- kernel 0: dtype detect -----------------------------------
__global__ void k_detect(const void* emb, int* flag){
    int tid = threadIdx.x;
    __shared__ int bad;
    if (tid == 0) bad = 0;
    __syncthreads();
    const unsigned short* u = (const unsigned short*)emb;
    int local = 0;
    for (int i = tid; i < 4096; i += 256){
        int e = (u[i] >> 7) & 0xFF;
        if (e > 140) local = 1;           // |v| > 2^13: impossible for real data
    }
    if (local) bad = 1;
    __syncthreads();
    if (tid == 0) *flag = bad;
}

// ---------------- prep kernels: convert weights to bf16 once ---------------
// wcat[r][0..2559] = w_ih[r], wcat[r][2560..3071] = w_hh[r]   (r = gate*512+n)
__global__ void k_prep_gates(const void* w_ih, const void* w_hh, bf16* __restrict__ wcat,
                             const int* __restrict__ flag){
    int ff = *flag;
    int r = blockIdx.x, tid = threadIdx.x;
    for (int i = tid*8; i < KCAT; i += 2048){
        bf16x8 v;
        if (i + 8 <= EIN){
            v = ldbf8(w_ih, (size_t)r*EIN + i, ff);
        } else if (i >= EIN){
            v = ldbf8(w_hh, (size_t)r*HD + (i - EIN), ff);
        } else {
#pragma unroll
            for (int j = 0; j < 8; ++j){
                int k = i + j;
                v[j] = (__bf16)((k < EIN) ? ld1(w_ih, (size_t)r*EIN + k, ff)
                                          : ld1(w_hh, (size_t)r*HD + (k - EIN), ff));
            }
        }
        *(bf16x8*)(wcat + (size_t)r*KCAT + i) = v;
    }
}
// vectorized convert, n must be divisible by 8
__global__ void k_prep_cvt8(const void* src, bf16* __restrict__ dst, size_t n8,
                            const int* __restrict__ flag){
    int ff = *flag;
    size_t idx = (size_t)blockIdx.x*256 + threadIdx.x;
    size_t stride = (size_t)gridDim.x*256;
    for (size_t i = idx; i < n8; i += stride)
        *(bf16x8*)(dst + i*8) = ldbf8(src, i*8, ff);
}

// ---------------- kernel 1: mean over feature positions (f32 out) ----------
__global__ void k_mean(const void* feat, float* __restrict__ mean_f,
                       const int* __restrict__ flag){
    int ff = *flag;
    int b = blockIdx.x, tid = threadIdx.x;
    for (int i = 0; i < ENC/256; ++i){
        int e = i*256 + tid;
        size_t base = (size_t)b*NF*ENC + e;
        float s = 0.f;
        for (int n = 0; n < NF; ++n) s += ld1(feat, base + (size_t)n*ENC, ff);
        mean_f[b*ENC + e] = s * (1.0f/49.0f);
    }
}

// ---------------- kernel 2: h0/c0 = mean_f @ [ihw|icw]^T + b (MFMA) --------
// M=32, N=1024 (h|c), K=2048. grid 64 (16 cols each), K split 4x512 over
// waves, LDS reduce. B rows loaded coalesced-vectorized via ldbf8.
__global__ void k_init_hc(const float* __restrict__ mean_f,
                          const void* ihw, const void* ihb,
                          const void* icw, const void* icb,
                          float* __restrict__ Hbuf, float* __restrict__ c_f32,
                          const int* __restrict__ flag){
    int ff = *flag;
    int tid = threadIdx.x, wave = tid>>6, lane = tid&63, quad = lane>>4, lq = lane&15;
    int n0 = blockIdx.x*16;
    int ng = n0 + lq;
    const void* w = (ng < HD) ? ihw : icw;
    size_t wrow = (size_t)(ng < HD ? ng : ng - HD)*ENC;
    floatx4 acc[2] = {{0,0,0,0},{0,0,0,0}};
    int kb = wave*512;
    for (int kk = 0; kk < 16; ++kk){
        int k = kb + kk*32 + quad*8;
        bf16x8 bfr = ldbf8(w, wrow + k, ff);
#pragma unroll
        for (int mt = 0; mt < 2; ++mt){
            bf16x8 afr = bf8_of_f32(mean_f + (size_t)(mt*16+lq)*ENC + k);
            acc[mt] = MFMA16(afr, bfr, acc[mt]);
        }
    }
    __shared__ float red[4][2][16][16];
#pragma unroll
    for (int mt = 0; mt < 2; ++mt)
        for (int r = 0; r < 4; ++r)
            red[wave][mt][quad*4+r][lq] = acc[mt][r];
    __syncthreads();
    for (int rep = 0; rep < 2; ++rep){
        int idx = rep*256 + tid;
        int mt = idx>>8, mm = (idx>>4)&15, nn = idx&15;
        float v = red[0][mt][mm][nn]+red[1][mt][mm][nn]+red[2][mt][mm][nn]+red[3][mt][mm][nn];
        int n_g = n0 + nn, b = mt*16 + mm;
        if (n_g < HD) Hbuf[b*HD + n_g]        = v + ld1(ihb, n_g, ff);
        else          c_f32[b*HD + (n_g-HD)]  = v + ld1(icb, n_g - HD, ff);
    }
}

// ---------------- kernel 3: u_hs = feat @ U_w^T + U_b (MFMA, f32 out) ------
__global__ void k_uhs(const void* feat, const void* U_w, const void* U_b,
                      float* __restrict__ u_hs, const int* __restrict__ flag){
    int ff = *flag;
    int tid = threadIdx.x, wave = tid>>6, lane = tid&63, quad = lane>>4, lq = lane&15;
    int m0 = blockIdx.x*16;
    int n0 = blockIdx.y*64 + wave*16;
    size_t arow = (size_t)(m0+lq)*ENC;
    size_t brow = (size_t)(n0+lq)*ENC;
    floatx4 acc = {0,0,0,0};
    for (int kk = 0; kk < ENC/32; ++kk){
        int k = kk*32 + quad*8;
        bf16x8 afr = ldbf8(feat, arow + k, ff);
        bf16x8 bfr = ldbf8(U_w,  brow + k, ff);
        acc = MFMA16(afr, bfr, acc);
    }
    float ub = ld1(U_b, n0+lq, ff);
    for (int r = 0; r < 4; ++r){
        int m = m0 + quad*4 + r;
        u_hs[(size_t)m*ATTD + n0 + lq] = acc[r] + ub;
    }
}

// ---------------- kernel 4: per-step attention (one block per b) -----------
// Builds lstm_in_bf[b][0..3071] = [embed | context | h_prev] (bf16 A-matrix)
// + writes alphas. All hot loads vectorized (float4 / bf16x8).
__global__ void k_step1(int t, const float* __restrict__ Hbuf_t,
                        const bf16* __restrict__ Ww_bf, const void* W_b,
                        const float* __restrict__ u_hs, const void* A_w, const void* A_b,
                        const int* __restrict__ captions, const void* emb, const void* feat,
                        bf16* __restrict__ lstm_in_bf, void* d_out,
                        const int* __restrict__ flag){
    int ff = *flag;
    int b = blockIdx.x, tid = threadIdx.x, wave = tid>>6, lane = tid&63;
    __shared__ float h_s[HD], wah_s[ATTD], aw_s[ATTD], sc_s[52], alpha_s[52];
    for (int i = tid; i < HD; i += 256){
        float hv = Hbuf_t[b*HD + i];
        h_s[i] = hv;
        lstm_in_bf[(size_t)b*KCAT + EIN + i] = f2bf(hv);
        aw_s[i] = ld1(A_w, i, ff);
    }
    int cap = captions[b*21 + t];
    for (int e = tid; e < EMB; e += 256)
        lstm_in_bf[(size_t)b*KCAT + e] = f2bf(ld1(emb, (size_t)cap*EMB + e, ff));
    __syncthreads();
    // phase A: w_ah[a] = h . W_w[a] + W_b[a]  (2 rows per thread, bf16x8 loads)
    for (int a = tid; a < ATTD; a += 256){
        const bf16* wr = Ww_bf + (size_t)a*HD;
        float acc = 0.f;
        for (int k = 0; k < HD; k += 8){
            bf16x8 wv = *(const bf16x8*)(wr + k);
            acc += (float)wv[0]*h_s[k+0] + (float)wv[1]*h_s[k+1]
                 + (float)wv[2]*h_s[k+2] + (float)wv[3]*h_s[k+3]
                 + (float)wv[4]*h_s[k+4] + (float)wv[5]*h_s[k+5]
                 + (float)wv[6]*h_s[k+6] + (float)wv[7]*h_s[k+7];
        }
        wah_s[a] = acc + ld1(W_b, a, ff);
    }
    __syncthreads();
    // phase B: scores[n] = A_w . tanh(u_hs[b,n,:] + w_ah) + A_b
    // lane owns 8 consecutive a's -> 2 float4 loads per n
    {
        int a0 = lane*8;
        for (int n = wave; n < NF; n += 4){
            const float* up = u_hs + (size_t)(b*NF + n)*ATTD + a0;
            float4 u0 = *(const float4*)up;
            float4 u1 = *(const float4*)(up + 4);
            float p = tanhf(u0.x + wah_s[a0+0])*aw_s[a0+0]
                    + tanhf(u0.y + wah_s[a0+1])*aw_s[a0+1]
                    + tanhf(u0.z + wah_s[a0+2])*aw_s[a0+2]
                    + tanhf(u0.w + wah_s[a0+3])*aw_s[a0+3]
                    + tanhf(u1.x + wah_s[a0+4])*aw_s[a0+4]
                    + tanhf(u1.y + wah_s[a0+5])*aw_s[a0+5]
                    + tanhf(u1.z + wah_s[a0+6])*aw_s[a0+6]
                    + tanhf(u1.w + wah_s[a0+7])*aw_s[a0+7];
            for (int off = 32; off; off >>= 1) p += __shfl_down(p, off);
            if (lane == 0) sc_s[n] = p + ld1(A_b, 0, ff);
        }
    }
    __syncthreads();
    // phase C: softmax over 49 (wave 0) + alpha output
    if (wave == 0){
        float v = (lane < NF) ? sc_s[lane] : -1e30f;
        float mx = v;
        for (int off = 32; off; off >>= 1) mx = fmaxf(mx, __shfl_down(mx, off));
        mx = __shfl(mx, 0);
        float e = (lane < NF) ? expf(v - mx) : 0.f;
        float s = e;
        for (int off = 32; off; off >>= 1) s += __shfl_down(s, off);
        s = __shfl(s, 0);
        if (lane < NF){
            float al = e / s;
            alpha_s[lane] = al;
            st1(d_out, (size_t)BB*TSTEPS*VCB + (size_t)b*(TSTEPS*NF) + t*NF + lane, al, ff);
        }
    }
    __syncthreads();
    // phase D: context[e] = sum_n alpha[n]*feat[b,n,e]; thread owns 8 contig e
    {
        int e0 = tid*8;
        float acc[8] = {0,0,0,0,0,0,0,0};
#pragma unroll 7
        for (int n = 0; n < NF; ++n){
            float al = alpha_s[n];
            size_t base = (size_t)b*NF*ENC + (size_t)n*ENC + e0;
            if (ff){
                const float* p = (const float*)feat + base;
                float4 v0 = *(const float4*)p, v1 = *(const float4*)(p+4);
                acc[0] += al*v0.x; acc[1] += al*v0.y; acc[2] += al*v0.z; acc[3] += al*v0.w;
                acc[4] += al*v1.x; acc[5] += al*v1.y; acc[6] += al*v1.z; acc[7] += al*v1.w;
            } else {
                bf16x8 v = *(const bf16x8*)((const bf16*)feat + base);
#pragma unroll
                for (int j = 0; j < 8; ++j) acc[j] += al*(float)v[j];
            }
        }
        bf16x8 st;
#pragma unroll
        for (int j = 0; j < 8; ++j) st[j] = (__bf16)acc[j];
        *(bf16x8*)(lstm_in_bf + (size_t)b*KCAT + EMB + e0) = st;
    }
}

// ---------------- kernel 5: gates GEMM (MFMA) + fused LSTM pointwise -------
// gates[32 x 2048] = lstm_in_bf[32 x 3072] @ wcat^T ; M=32, N=2048, K=3072.
// grid (128, 2): x = 4 hidden cols x 4 gates (16 interleaved B-rows),
// y = 16-row m-half. K split 4 ways across waves, LDS reduce, pointwise.
__global__ void k_step2(const bf16* __restrict__ lstm_in_bf, const bf16* __restrict__ wcat,
                        const void* b_ih, const void* b_hh,
                        float* __restrict__ c_f32, float* __restrict__ Hbuf_next,
                        bf16* __restrict__ Hall_bf_t, const int* __restrict__ flag){
    int ff = *flag;
    int tid = threadIdx.x, ks = tid>>6, lane = tid&63, quad = lane>>4, lq = lane&15;
    int n0 = blockIdx.x*4;
    int m0 = blockIdx.y*16;
    int gate = lq>>2, j = lq&3;
    const bf16* brow = wcat + (size_t)(gate*HD + n0 + j)*KCAT;
    const bf16* arow = lstm_in_bf + (size_t)(m0 + lq)*KCAT;
    floatx4 acc = {0,0,0,0};
    int kb = ks*768;
    for (int kk = 0; kk < 24; ++kk){
        int k = kb + kk*32 + quad*8;
        bf16x8 bfr = *(const bf16x8*)(brow + k);
        bf16x8 afr = *(const bf16x8*)(arow + k);
        acc = MFMA16(afr, bfr, acc);
    }
    __shared__ float red[4][16][16];
#pragma unroll
    for (int r = 0; r < 4; ++r) red[ks][quad*4+r][lq] = acc[r];
    __syncthreads();
    if (tid < 64){
        int mm = tid & 15, jj = tid >> 4;     // jj 0..3
        int bb = m0 + mm, col = n0 + jj;
        float G[4];
#pragma unroll
        for (int g = 0; g < 4; ++g){
            int lqv = g*4 + jj;
            float s = red[0][mm][lqv] + red[1][mm][lqv] + red[2][mm][lqv] + red[3][mm][lqv];
            G[g] = s + ld1(b_ih, g*HD + col, ff) + ld1(b_hh, g*HD + col, ff);
        }
        float c_old = c_f32[bb*HD + col];
        float c_new = sigm(G[1])*c_old + sigm(G[0])*tanhf(G[2]);
        float h_new = sigm(G[3])*tanhf(c_new);
        c_f32[bb*HD + col] = c_new;
        Hbuf_next[bb*HD + col] = h_new;
        Hall_bf_t[(size_t)bb*HD + col] = f2bf(h_new);
    }
}

// ---------------- kernel 6: preds = Hall_bf @ fcnw_bf^T + fcn_b ------------
// M=640 (m=t*32+b), N=30522, K=512. grid 477 (x only): fcn_w read EXACTLY once.
__global__ void __launch_bounds__(256) k_fcn(const bf16* __restrict__ Hall_bf,
                                             const bf16* __restrict__ fcnw_bf,
                                             const void* fcn_b, void* d_out,
                                             const int* __restrict__ flag){
    int ff = *flag;
    int tid = threadIdx.x, wave = tid>>6, lane = tid&63, quad = lane>>4, lq = lane&15;
    int n0 = blockIdx.x*64 + wave*16;
    int v = n0 + lq;
    int vc = (v < VCB) ? v : (VCB-1);
    const bf16* brow = fcnw_bf + (size_t)vc*HD;
    bf16x8 bfr[16];
#pragma unroll
    for (int kk = 0; kk < 16; ++kk) bfr[kk] = *(const bf16x8*)(brow + kk*32 + quad*8);
    float bias = ld1(fcn_b, vc, ff);
    for (int mt = 0; mt < 40; ++mt){
        const bf16* arow = Hall_bf + (size_t)(mt*16 + lq)*HD;
        floatx4 acc = {0,0,0,0};
#pragma unroll
        for (int kk = 0; kk < 16; ++kk){
            bf16x8 afr = *(const bf16x8*)(arow + kk*32 + quad*8);
            acc = MFMA16(afr, bfr[kk], acc);
        }
        if (v < VCB){
#pragma unroll
            for (int r = 0; r < 4; ++r){
                int m = mt*16 + quad*4 + r;
                int b = m & 31, tt = m >> 5;
                st1(d_out, (size_t)b*(TSTEPS*VCB) + (size_t)tt*VCB + v, acc[r] + bias, ff);
            }
        }
    }
}

// ---------------- host launch ---------------------------------------------
extern "C" void kernel_launch(void* const* d_in, const int* in_sizes, int n_in,
                              void* d_out, int out_size, void* d_ws, size_t ws_size,
                              hipStream_t stream) {
    const void* feat  = d_in[0];
    const int*  caps  = (const int*)d_in[1];
    const void* emb   = d_in[2];
    const void* W_w   = d_in[3];
    const void* W_b   = d_in[4];
    const void* U_w   = d_in[5];
    const void* U_b   = d_in[6];
    const void* A_w   = d_in[7];
    const void* A_b   = d_in[8];
    const void* ihw   = d_in[9];
    const void* ihb   = d_in[10];
    const void* icw   = d_in[11];
    const void* icb   = d_in[12];
    const void* w_ih  = d_in[13];
    const void* w_hh  = d_in[14];
    const void* b_ih  = d_in[15];
    const void* b_hh  = d_in[16];
    const void* fcn_w = d_in[17];
    const void* fcn_b = d_in[18];

    // workspace layout (16B-aligned)
    char* ws = (char*)d_ws;
    size_t off = 0;
    float* u_hs    = (float*)(ws + off); off += (size_t)BB*NF*ATTD*4;       // 3.2 MB
    float* c_f32   = (float*)(ws + off); off += (size_t)BB*HD*4;            // 64 KB
    float* mean_f  = (float*)(ws + off); off += (size_t)BB*ENC*4;           // 256 KB
    float* Hbuf    = (float*)(ws + off); off += (size_t)(TSTEPS+1)*BB*HD*4; // 1.38 MB
    bf16*  lstm_in = (bf16*) (ws + off); off += (size_t)BB*KCAT*2;          // 192 KB
    bf16*  Hall_bf = (bf16*) (ws + off); off += (size_t)TSTEPS*BB*HD*2;     // 640 KB
    bf16*  wcat    = (bf16*) (ws + off); off += (size_t)4*HD*KCAT*2;        // 12.6 MB
    bf16*  fcnw_bf = (bf16*) (ws + off); off += (size_t)VCB*HD*2;           // 31.25 MB
    bf16*  Ww_bf   = (bf16*) (ws + off); off += (size_t)ATTD*HD*2;          // 512 KB
    int*   flag    = (int*)  (ws + off); off += 256;
    if (ws_size < off) return;

    k_detect    <<<1, 256, 0, stream>>>(emb, flag);
    k_prep_gates<<<2048, 256, 0, stream>>>(w_ih, w_hh, wcat, flag);
    k_prep_cvt8 <<<2048, 256, 0, stream>>>(fcn_w, fcnw_bf, (size_t)VCB*HD/8, flag);
    k_prep_cvt8 <<<128, 256, 0, stream>>>(W_w, Ww_bf, (size_t)ATTD*HD/8, flag);
    k_mean      <<<BB, 256, 0, stream>>>(feat, mean_f, flag);
    k_init_hc   <<<64, 256, 0, stream>>>(mean_f, ihw, ihb, icw, icb, Hbuf, c_f32, flag);
    k_uhs       <<<dim3(98, 8), 256, 0, stream>>>(feat, U_w, U_b, u_hs, flag);

    for (int t = 0; t < TSTEPS; ++t){
        float* h_t = Hbuf + (size_t)t*BB*HD;
        k_step1<<<BB, 256, 0, stream>>>(t, h_t, Ww_bf, W_b, u_hs, A_w, A_b, caps, emb, feat,
                                        lstm_in, d_out, flag);
        k_step2<<<dim3(128, 2), 256, 0, stream>>>(lstm_in, wcat, b_ih, b_hh, c_f32,
                                                  h_t + (size_t)BB*HD,
                                                  Hall_bf + (size_t)t*BB*HD, flag);
    }
    k_fcn<<<477, 256, 0, stream>>>(Hall_bf, fcnw_bf, fcn_b, d_out, flag);
}